// Round 10
// baseline (8330.646 us; speedup 1.0000x reference)
//
#include <hip/hip_runtime.h>
#include <stdint.h>

// RTRBM CD-1: bit-exact replication of the JAX-CPU reference.
// Recurrence independent per batch column -> no grid sync.
// Phase A: WV2[bg][t][h][2] = W @ v_t (FMA exact: v binary), into out_v region.
// Phase B: hidden_cols — 128 blocks x 1024 threads (2 cols/block, k-panel split
//          at Eigen kc=288), UTP coalesced float2 loads software-pipelined in
//          register double-buffers, r ping-pong in LDS read as float4,
//          RNG on panel-1 threads, h out as ballot-packed bits.
// Phase E: expand bits -> out_r floats.
// Phase C: all visible steps from out_r floats.
// Sizes: V=784, H=500, T=256, B=256. RNG: threefry partitionable.
// Eigen MT blocking (AVX no-FMA jaxlib): kc=288. K=784 -> [288,288,208]; K=500 -> [288,212].
#define NV 784
#define NH 500
#define TT 256
#define BB 256
#define NBG 128   // b-pairs

typedef float f2v __attribute__((ext_vector_type(2)));

// ---------------- threefry2x32 (JAX PRNG), exact ----------------
__device__ __forceinline__ void tf2x32(uint32_t ks0, uint32_t ks1,
                                       uint32_t x0, uint32_t x1,
                                       uint32_t& y0, uint32_t& y1) {
  uint32_t ks2 = ks0 ^ ks1 ^ 0x1BD11BDAu;
  x0 += ks0; x1 += ks1;
#define TFROT(r) { x0 += x1; x1 = (x1 << (r)) | (x1 >> (32 - (r))); x1 ^= x0; }
  TFROT(13) TFROT(15) TFROT(26) TFROT(6)
  x0 += ks1; x1 += ks2 + 1u;
  TFROT(17) TFROT(29) TFROT(16) TFROT(24)
  x0 += ks2; x1 += ks0 + 2u;
  TFROT(13) TFROT(15) TFROT(26) TFROT(6)
  x0 += ks0; x1 += ks1 + 3u;
  TFROT(17) TFROT(29) TFROT(16) TFROT(24)
  x0 += ks1; x1 += ks2 + 4u;
  TFROT(13) TFROT(15) TFROT(26) TFROT(6)
  x0 += ks2; x1 += ks0 + 5u;
#undef TFROT
  y0 = x0; y1 = x1;
}

__device__ __forceinline__ float jax_uniform(uint32_t bits) {
#pragma clang fp contract(off)
  float f = __uint_as_float((bits >> 9) | 0x3F800000u);
  return f - 1.0f;
}

// PARTITIONABLE random_bits, 32-bit: bits[j] = y0 ^ y1 of threefry(key; 0, j)
__device__ __forceinline__ uint32_t draw_bits(uint32_t k0, uint32_t k1,
                                              uint32_t j) {
  uint32_t y0, y1;
  tf2x32(k0, k1, 0u, j, y0, y1);
  return y0 ^ y1;
}

// ---------------- XLA CPU exp (Cephes/Eigen poly, no FMA) ----------------
__device__ __forceinline__ float xla_expf(float x) {
#pragma clang fp contract(off)
  float xc = fminf(fmaxf(x, -88.3762626647949f), 88.3762626647950f);
  float fx = floorf(xc * 1.44269504088896341f + 0.5f);
  float tmp = 0.693359375f * fx;
  float z = -2.12194440e-4f * fx;
  float xr = xc - tmp;
  xr = xr - z;
  z = xr * xr;
  float y = xr * 1.9875691500e-4f + 1.3981999507e-3f;
  y = y * xr + 8.3334519073e-3f;
  y = y * xr + 4.1665795894e-2f;
  y = y * xr + 1.6666665459e-1f;
  y = y * xr + 5.0000001201e-1f;
  y = y * z + xr;
  y = 1.0f + y;
  int e = (int)fx;
  float pow2 = __int_as_float((uint32_t)(e + 127) << 23);
  return y * pow2;
}

__device__ __forceinline__ float xla_sigmoid(float x) {
#pragma clang fp contract(off)
  float e = xla_expf(-x);
  float d = 1.0f + e;
  return 1.0f / d;
}

// ---------------- key derivation (PARTITIONABLE split) ----------------
__global__ void init_keys(uint32_t* __restrict__ keys /* [256][4] */) {
  int t = threadIdx.x;
  if (t >= TT) return;
  uint32_t kt0, kt1;
  tf2x32(0u, 123u, 0u, (uint32_t)t, kt0, kt1);
  uint32_t a0, a1, b0, b1;
  tf2x32(kt0, kt1, 0u, 0u, a0, a1);  // k1 (hidden)
  tf2x32(kt0, kt1, 0u, 1u, b0, b1);  // k2 (visible)
  keys[4 * t + 0] = a0;
  keys[4 * t + 1] = a1;
  keys[4 * t + 2] = b0;
  keys[4 * t + 3] = b1;
}

// ---------------- W transpose: WT[i][k] = W[k][i] ----------------
__global__ __launch_bounds__(256) void wt_kernel(const float* __restrict__ W,
                                                 float* __restrict__ WT) {
  const int i = blockIdx.x;           // 0..783
  for (int k = threadIdx.x; k < NH; k += 256)
    WT[(size_t)i * NH + k] = W[(size_t)k * NV + i];
}

// ---------------- U transpose+pair: UTP[p][h] = (U[h][2p], U[h][2p+1]) ----------------
__global__ __launch_bounds__(512) void ut_kernel(const float* __restrict__ U,
                                                 float2* __restrict__ UTP) {
  const int p = blockIdx.x;           // 0..249
  const int h = threadIdx.x;          // 0..511
  float2 w;
  if (h < NH) {
    w.x = U[(size_t)h * NH + 2 * p];
    w.y = U[(size_t)h * NH + 2 * p + 1];
  } else {
    w.x = 0.0f; w.y = 0.0f;
  }
  UTP[(size_t)p * 512 + h] = w;
}

// ---------------- Phase A: WV2[bg][t][h][2] = (W @ v_t)[h][b] ----------------
// fmaf(w, x, s) == s + w*x bit-exactly because x in {0,1} (w*x exact).
#define HT_A 25   // 500/25 = 20 blocks per t
__global__ __launch_bounds__(256) void wv_gemm(
    const float* __restrict__ v, const float* __restrict__ W,
    float* __restrict__ wv2) {
#pragma clang fp contract(off)
  const int b = threadIdx.x;
  const int h0 = blockIdx.x * HT_A;
  const int t = blockIdx.y;
  const float* vcol = v + (size_t)t * BB + b;   // element k: vcol[k * TT*BB]

  float acc[HT_A];
#pragma unroll
  for (int r = 0; r < HT_A; ++r) acc[r] = 0.0f;

  const int pb[4] = {0, 288, 576, 784};   // kc=288 panels
#pragma unroll 1
  for (int p = 0; p < 3; ++p) {
    float ps[HT_A];
#pragma unroll
    for (int r = 0; r < HT_A; ++r) ps[r] = 0.0f;
    const int k0 = pb[p], k1 = pb[p + 1];
#pragma unroll 16
    for (int k = k0; k < k1; ++k) {
      float x = vcol[(size_t)k * (TT * BB)];
#pragma unroll
      for (int r = 0; r < HT_A; ++r)
        ps[r] = __builtin_fmaf(W[(size_t)(h0 + r) * NV + k], x, ps[r]);
    }
#pragma unroll
    for (int r = 0; r < HT_A; ++r) acc[r] = acc[r] + ps[r];
  }

  // LDS transpose so stores are h-contiguous runs of 50 floats per bg
  __shared__ float al[HT_A][BB];
#pragma unroll
  for (int r = 0; r < HT_A; ++r) al[r][b] = acc[r];
  __syncthreads();

  // write 50-float runs: wv2[bg][t][h0*2 .. h0*2+49]
  const int tid = b;
  const int sub = tid / 50;       // 0..4 (5 bg per iter), tid<250 active
  const int idx = tid % 50;       // h = h0 + idx/2, j = idx&1
#pragma unroll 1
  for (int it = 0; it < 26; ++it) {
    const int bg = it * 5 + sub;
    if (tid < 250 && bg < NBG) {
      wv2[((size_t)bg * TT + t) * 1024 + h0 * 2 + idx] =
          al[idx >> 1][2 * bg + (idx & 1)];
    }
  }
}

// ---------------- Phase B dot: software-pipelined panel dot ----------------
// Strict ascending k (k = 2p then 2p+1), mul-then-add (no FMA: r arbitrary).
// UTP loads double-buffered in registers, statically indexed throughout.
template <int PBASE, int NPAIR>
__device__ __forceinline__ f2v dot_panel(const float2* __restrict__ UTPh,
                                         const float4* __restrict__ rof4) {
#pragma clang fp contract(off)
  constexpr int CH = 8;
  constexpr int NC = NPAIR / CH;              // full chunks
  constexpr int REM = NPAIR - NC * CH;        // remainder pairs
  float2 bufA[CH], bufB[CH];
  f2v acc; acc.x = 0.0f; acc.y = 0.0f;
#pragma unroll
  for (int i = 0; i < CH; ++i) bufA[i] = UTPh[(size_t)(PBASE + i) * 512];
#pragma unroll 1
  for (int c = 0; c < NC; ++c) {
    const int pb = PBASE + c * CH;
    if (c + 1 < NC) {
#pragma unroll
      for (int i = 0; i < CH; ++i)
        bufB[i] = UTPh[(size_t)(pb + CH + i) * 512];
    } else if (REM > 0) {
#pragma unroll
      for (int i = 0; i < REM; ++i)
        bufB[i] = UTPh[(size_t)(pb + CH + i) * 512];
    }
#pragma unroll
    for (int i = 0; i < CH; ++i) {
      const float4 r4 = rof4[pb + i];         // ds_read_b128: pairs (2k, 2k+1)
      f2v ux; ux.x = bufA[i].x; ux.y = bufA[i].x;
      f2v uy; uy.x = bufA[i].y; uy.y = bufA[i].y;
      f2v r0; r0.x = r4.x; r0.y = r4.y;
      f2v r1; r1.x = r4.z; r1.y = r4.w;
      acc = acc + ux * r0;    // k = 2p
      acc = acc + uy * r1;    // k = 2p+1
    }
#pragma unroll
    for (int i = 0; i < CH; ++i) bufA[i] = bufB[i];
  }
#pragma unroll
  for (int i = 0; i < REM; ++i) {
    const int p = PBASE + NC * CH + i;
    const float4 r4 = rof4[p];
    f2v ux; ux.x = bufA[i].x; ux.y = bufA[i].x;
    f2v uy; uy.x = bufA[i].y; uy.y = bufA[i].y;
    f2v r0; r0.x = r4.x; r0.y = r4.y;
    f2v r1; r1.x = r4.z; r1.y = r4.w;
    acc = acc + ux * r0;
    acc = acc + uy * r1;
  }
  return acc;
}

// ---------------- Phase B: per-b-pair recurrence, panel-split 1024 threads ----
// tid 0-511 (pan 0): panel 0 (pairs 0..143) + epilogue/sample/pack.
// tid 512-1023 (pan 1): panel 1 (pairs 144..249) + RNG draws.
// acc = a0 + ps1 == (0+panel0)+panel1 of the reference.
__global__ __launch_bounds__(1024) void hidden_cols(
    const float2* __restrict__ UTP, const float* __restrict__ b_h,
    const float* __restrict__ b_init, const uint32_t* __restrict__ keys,
    const float* __restrict__ wv2, uint32_t* __restrict__ hbw) {
#pragma clang fp contract(off)
  const int tid = threadIdx.x;
  const int pan = tid >> 9;           // wave-uniform
  const int h = tid & 511;
  const int hs = (h < NH) ? h : 0;
  const int bg = (int)blockIdx.x;
  const int b0 = 2 * bg;

  __shared__ f2v rA[512];             // r ping-pong, [h] -> (col0,col1)
  __shared__ f2v rB[512];
  __shared__ f2v ps_l[512];           // panel-1 partials
  __shared__ f2v u_l[512];            // uniforms
  __shared__ uint32_t keyl[2 * TT];

  if (tid < 2 * TT) keyl[tid] = keys[4 * (tid >> 1) + (tid & 1)];
  if (pan == 0) { f2v z; z.x = 0.0f; z.y = 0.0f; rA[h] = z; }  // r_lag(0)=0
  const float bh = b_h[hs], bi = b_init[hs];
  const float2* __restrict__ UTPh = UTP + h;
  __syncthreads();

#pragma unroll 1
  for (int t = 0; t < TT; ++t) {
    const f2v* __restrict__ ro = (t & 1) ? rB : rA;
    f2v* __restrict__ rn = (t & 1) ? rA : rB;
    const float4* __restrict__ rof4 = (const float4*)ro;

    f2v wvp; wvp.x = 0.0f; wvp.y = 0.0f;
    f2v a;
    if (pan == 0) {
      wvp = *(const f2v*)&wv2[((size_t)bg * TT + t) * 1024 + h * 2];
      a = dot_panel<0, 144>(UTPh, rof4);      // k = 0..287
    } else {
      a = dot_panel<144, 106>(UTPh, rof4);    // k = 288..499
      ps_l[h] = a;
      const uint32_t k0 = keyl[2 * t], k1 = keyl[2 * t + 1];
      f2v u;
      u.x = jax_uniform(draw_bits(k0, k1, (uint32_t)(h * BB + b0)));
      u.y = jax_uniform(draw_bits(k0, k1, (uint32_t)(h * BB + b0 + 1)));
      u_l[h] = u;
    }
    __syncthreads();

    if (pan == 0) {
      const f2v ps = ps_l[h];
      const float acc0 = a.x + ps.x;          // == (0+panel0)+panel1
      const float acc1 = a.y + ps.y;
      const float bias = (t == 0) ? bi : bh;
      const float pre0 = (wvp.x + acc0) + bias;   // reference order
      const float pre1 = (wvp.y + acc1) + bias;
      const float pp0 = xla_sigmoid(pre0);
      const float pp1 = xla_sigmoid(pre1);
      const f2v u = u_l[h];
      const bool hm0 = u.x < pp0;
      const bool hm1 = u.y < pp1;

      const unsigned long long m0 = __ballot(hm0);
      const unsigned long long m1 = __ballot(hm1);
      const int lh = h & 63;
      if (lh == 0) {
        uint2 w; w.x = (uint32_t)m0; w.y = (uint32_t)m1;
        *(uint2*)&hbw[(size_t)(h >> 5) * (TT * BB) + (size_t)t * BB + b0] = w;
      }
      if (lh == 32) {
        uint2 w; w.x = (uint32_t)(m0 >> 32); w.y = (uint32_t)(m1 >> 32);
        *(uint2*)&hbw[(size_t)(h >> 5) * (TT * BB) + (size_t)t * BB + b0] = w;
      }

      f2v pv; pv.x = pp0; pv.y = pp1;
      rn[h] = pv;
    }
    __syncthreads();
  }
}

// ---------------- Phase E: expand packed h bits -> out_r floats ----------------
__global__ __launch_bounds__(256) void expand_r(
    const uint32_t* __restrict__ hbw, float* __restrict__ out_r) {
  const int h = blockIdx.x;           // 0..499
  const int b = threadIdx.x;
  const uint32_t sh = (uint32_t)(h & 31);
  const uint32_t* src = hbw + (size_t)(h >> 5) * (TT * BB);
  float* dst = out_r + (size_t)h * (TT * BB);
#pragma unroll 4
  for (int t = 0; t < TT; ++t) {
    uint32_t w = src[t * BB + b];
    dst[t * BB + b] = (float)((w >> sh) & 1u);
  }
}

// ---------------- Phase C: all visible steps; h read from out_r ----------------
// fmaf(w, h, s) == s + w*h bit-exactly because h in {0,1}.
#define IT_C 16   // 784/16 = 49 i-tiles
__global__ __launch_bounds__(256) void visible_big(
    const float* __restrict__ WT, const float* __restrict__ b_v,
    const uint32_t* __restrict__ keys, const float* __restrict__ hplane,
    float* __restrict__ out_v) {
#pragma clang fp contract(off)
  const int b = threadIdx.x;
  const int i0 = blockIdx.x * IT_C;
  const int t = blockIdx.y;
  const float* hcol = hplane + (size_t)t * BB + b;  // element k: hcol[k * TT*BB]

  float acc[IT_C];
#pragma unroll
  for (int r = 0; r < IT_C; ++r) acc[r] = 0.0f;

  const int pb[3] = {0, 288, 500};
#pragma unroll 1
  for (int p = 0; p < 2; ++p) {
    float ps[IT_C];
#pragma unroll
    for (int r = 0; r < IT_C; ++r) ps[r] = 0.0f;
    const int k0 = pb[p], k1 = pb[p + 1];
#pragma unroll 8
    for (int k = k0; k < k1; ++k) {
      float hh = hcol[(size_t)k * (TT * BB)];
#pragma unroll
      for (int r = 0; r < IT_C; ++r)
        ps[r] = __builtin_fmaf(WT[(size_t)(i0 + r) * NH + k], hh, ps[r]);
    }
#pragma unroll
    for (int r = 0; r < IT_C; ++r) acc[r] = acc[r] + ps[r];
  }

  const uint32_t key0 = keys[4 * t + 2], key1 = keys[4 * t + 3];
#pragma unroll
  for (int r = 0; r < IT_C; ++r) {
    const int i = i0 + r;
    float pre = acc[r] + b_v[i];
    float p = xla_sigmoid(pre);
    uint32_t j = (uint32_t)(i * BB + b);
    float u = jax_uniform(draw_bits(key0, key1, j));
    out_v[(size_t)i * (TT * BB) + (size_t)t * BB + b] = (u < p) ? 1.0f : 0.0f;
  }
}

extern "C" void kernel_launch(void* const* d_in, const int* in_sizes, int n_in,
                              void* d_out, int out_size, void* d_ws, size_t ws_size,
                              hipStream_t stream) {
  const float* v      = (const float*)d_in[0];
  const float* W      = (const float*)d_in[1];
  const float* U      = (const float*)d_in[2];
  const float* b_h    = (const float*)d_in[3];
  const float* b_v    = (const float*)d_in[4];
  const float* b_init = (const float*)d_in[5];

  float* out_v = (float*)d_out;                       // (784,256,256) = 205.5 MB
  float* out_r = out_v + (size_t)NV * TT * BB;        // (500,256,256) = 131 MB

  // wv2 staged inside the out_v region (134.2 MB <= 205.5 MB); dead before
  // phase C overwrites out_v. UTP staged at the head of the out_r region
  // (1.02 MB); dead before phase E overwrites out_r.
  float* wv2 = out_v;
  float2* UTP = (float2*)out_r;

  // ws: WT (1.57 MB) + keys (4 KB) + hbw (4.19 MB)
  float* WT = (float*)d_ws;
  uint32_t* keys = (uint32_t*)(WT + (size_t)NV * NH);
  uint32_t* hbw = keys + TT * 4;   // [16][256][256] u32

  init_keys<<<1, 256, 0, stream>>>(keys);
  wt_kernel<<<NV, 256, 0, stream>>>(W, WT);
  ut_kernel<<<250, 512, 0, stream>>>(U, UTP);

  dim3 gA(NH / HT_A, TT);
  wv_gemm<<<gA, 256, 0, stream>>>(v, W, wv2);

  hidden_cols<<<NBG, 1024, 0, stream>>>(UTP, b_h, b_init, keys, wv2, hbw);

  expand_r<<<NH, 256, 0, stream>>>(hbw, out_r);

  dim3 gC(NV / IT_C, TT);
  visible_big<<<gC, 256, 0, stream>>>(WT, b_v, keys, out_r, out_v);
}

// Round 11
// 6753.721 us; speedup vs baseline: 1.2335x; 1.2335x over previous
//
#include <hip/hip_runtime.h>
#include <stdint.h>

// RTRBM CD-1: bit-exact replication of the JAX-CPU reference.
// Recurrence independent per batch column; additionally h-SPLIT across block
// pairs: block bid handles bg = bid&127, h-half = bid>>7 (h in [0,256) or
// [256,500)). Per-t r-half exchange through L2 via relaxed agent atomics +
// monotone progress counters — NO cache fences (no wbl2/inv storms).
// Phase A: WV2[bg][t][h][2] = W @ v_t (FMA exact: v binary), into out_v region.
// Phase B: hidden_pair — 256 blocks x 512 threads (2 cols, half the h-rows,
//          k-panel split at Eigen kc=288 across thread halves), U streamed
//          coalesced (UTP), r full in LDS, h out as ballot-packed bits.
// Phase E: expand bits -> out_r floats.
// Phase C: all visible steps from out_r floats.
// Sizes: V=784, H=500, T=256, B=256. RNG: threefry partitionable.
// Eigen MT blocking (AVX no-FMA jaxlib): kc=288. K=784 -> [288,288,208]; K=500 -> [288,212].
#define NV 784
#define NH 500
#define TT 256
#define BB 256
#define NBG 128   // b-pairs

typedef float f2v __attribute__((ext_vector_type(2)));

// ---------------- threefry2x32 (JAX PRNG), exact ----------------
__device__ __forceinline__ void tf2x32(uint32_t ks0, uint32_t ks1,
                                       uint32_t x0, uint32_t x1,
                                       uint32_t& y0, uint32_t& y1) {
  uint32_t ks2 = ks0 ^ ks1 ^ 0x1BD11BDAu;
  x0 += ks0; x1 += ks1;
#define TFROT(r) { x0 += x1; x1 = (x1 << (r)) | (x1 >> (32 - (r))); x1 ^= x0; }
  TFROT(13) TFROT(15) TFROT(26) TFROT(6)
  x0 += ks1; x1 += ks2 + 1u;
  TFROT(17) TFROT(29) TFROT(16) TFROT(24)
  x0 += ks2; x1 += ks0 + 2u;
  TFROT(13) TFROT(15) TFROT(26) TFROT(6)
  x0 += ks0; x1 += ks1 + 3u;
  TFROT(17) TFROT(29) TFROT(16) TFROT(24)
  x0 += ks1; x1 += ks2 + 4u;
  TFROT(13) TFROT(15) TFROT(26) TFROT(6)
  x0 += ks2; x1 += ks0 + 5u;
#undef TFROT
  y0 = x0; y1 = x1;
}

__device__ __forceinline__ float jax_uniform(uint32_t bits) {
#pragma clang fp contract(off)
  float f = __uint_as_float((bits >> 9) | 0x3F800000u);
  return f - 1.0f;
}

// PARTITIONABLE random_bits, 32-bit: bits[j] = y0 ^ y1 of threefry(key; 0, j)
__device__ __forceinline__ uint32_t draw_bits(uint32_t k0, uint32_t k1,
                                              uint32_t j) {
  uint32_t y0, y1;
  tf2x32(k0, k1, 0u, j, y0, y1);
  return y0 ^ y1;
}

// ---------------- XLA CPU exp (Cephes/Eigen poly, no FMA) ----------------
__device__ __forceinline__ float xla_expf(float x) {
#pragma clang fp contract(off)
  float xc = fminf(fmaxf(x, -88.3762626647949f), 88.3762626647950f);
  float fx = floorf(xc * 1.44269504088896341f + 0.5f);
  float tmp = 0.693359375f * fx;
  float z = -2.12194440e-4f * fx;
  float xr = xc - tmp;
  xr = xr - z;
  z = xr * xr;
  float y = xr * 1.9875691500e-4f + 1.3981999507e-3f;
  y = y * xr + 8.3334519073e-3f;
  y = y * xr + 4.1665795894e-2f;
  y = y * xr + 1.6666665459e-1f;
  y = y * xr + 5.0000001201e-1f;
  y = y * z + xr;
  y = 1.0f + y;
  int e = (int)fx;
  float pow2 = __int_as_float((uint32_t)(e + 127) << 23);
  return y * pow2;
}

__device__ __forceinline__ float xla_sigmoid(float x) {
#pragma clang fp contract(off)
  float e = xla_expf(-x);
  float d = 1.0f + e;
  return 1.0f / d;
}

// ---------------- key derivation (PARTITIONABLE split) ----------------
__global__ void init_keys(uint32_t* __restrict__ keys /* [256][4] */) {
  int t = threadIdx.x;
  if (t >= TT) return;
  uint32_t kt0, kt1;
  tf2x32(0u, 123u, 0u, (uint32_t)t, kt0, kt1);
  uint32_t a0, a1, b0, b1;
  tf2x32(kt0, kt1, 0u, 0u, a0, a1);  // k1 (hidden)
  tf2x32(kt0, kt1, 0u, 1u, b0, b1);  // k2 (visible)
  keys[4 * t + 0] = a0;
  keys[4 * t + 1] = a1;
  keys[4 * t + 2] = b0;
  keys[4 * t + 3] = b1;
}

// ---------------- W transpose: WT[i][k] = W[k][i] ----------------
__global__ __launch_bounds__(256) void wt_kernel(const float* __restrict__ W,
                                                 float* __restrict__ WT) {
  const int i = blockIdx.x;           // 0..783
  for (int k = threadIdx.x; k < NH; k += 256)
    WT[(size_t)i * NH + k] = W[(size_t)k * NV + i];
}

// ---------------- U transpose+pair: UTP[p][h] = (U[h][2p], U[h][2p+1]) ----------------
__global__ __launch_bounds__(512) void ut_kernel(const float* __restrict__ U,
                                                 float2* __restrict__ UTP) {
  const int p = blockIdx.x;           // 0..249
  const int h = threadIdx.x;          // 0..511
  float2 w;
  if (h < NH) {
    w.x = U[(size_t)h * NH + 2 * p];
    w.y = U[(size_t)h * NH + 2 * p + 1];
  } else {
    w.x = 0.0f; w.y = 0.0f;
  }
  UTP[(size_t)p * 512 + h] = w;
}

// ---------------- Phase A: WV2[bg][t][h][2] = (W @ v_t)[h][b] ----------------
// fmaf(w, x, s) == s + w*x bit-exactly because x in {0,1} (w*x exact).
#define HT_A 25   // 500/25 = 20 blocks per t
__global__ __launch_bounds__(256) void wv_gemm(
    const float* __restrict__ v, const float* __restrict__ W,
    float* __restrict__ wv2) {
#pragma clang fp contract(off)
  const int b = threadIdx.x;
  const int h0 = blockIdx.x * HT_A;
  const int t = blockIdx.y;
  const float* vcol = v + (size_t)t * BB + b;   // element k: vcol[k * TT*BB]

  float acc[HT_A];
#pragma unroll
  for (int r = 0; r < HT_A; ++r) acc[r] = 0.0f;

  const int pb[4] = {0, 288, 576, 784};   // kc=288 panels
#pragma unroll 1
  for (int p = 0; p < 3; ++p) {
    float ps[HT_A];
#pragma unroll
    for (int r = 0; r < HT_A; ++r) ps[r] = 0.0f;
    const int k0 = pb[p], k1 = pb[p + 1];
#pragma unroll 16
    for (int k = k0; k < k1; ++k) {
      float x = vcol[(size_t)k * (TT * BB)];
#pragma unroll
      for (int r = 0; r < HT_A; ++r)
        ps[r] = __builtin_fmaf(W[(size_t)(h0 + r) * NV + k], x, ps[r]);
    }
#pragma unroll
    for (int r = 0; r < HT_A; ++r) acc[r] = acc[r] + ps[r];
  }

  // LDS transpose so stores are h-contiguous runs of 50 floats per bg
  __shared__ float al[HT_A][BB];
#pragma unroll
  for (int r = 0; r < HT_A; ++r) al[r][b] = acc[r];
  __syncthreads();

  // write 50-float runs: wv2[bg][t][h0*2 .. h0*2+49]
  const int tid = b;
  const int sub = tid / 50;       // 0..4 (5 bg per iter), tid<250 active
  const int idx = tid % 50;       // h = h0 + idx/2, j = idx&1
#pragma unroll 1
  for (int it = 0; it < 26; ++it) {
    const int bg = it * 5 + sub;
    if (tid < 250 && bg < NBG) {
      wv2[((size_t)bg * TT + t) * 1024 + h0 * 2 + idx] =
          al[idx >> 1][2 * bg + (idx & 1)];
    }
  }
}

// ---------------- Phase B dot: software-pipelined panel dot ----------------
// Strict ascending k (k = 2p then 2p+1), mul-then-add (no FMA: r arbitrary).
// UTP loads double-buffered in registers, statically indexed throughout.
template <int PBASE, int NPAIR>
__device__ __forceinline__ f2v dot_panel(const float2* __restrict__ UTPh,
                                         const float4* __restrict__ rof4) {
#pragma clang fp contract(off)
  constexpr int CH = 8;
  constexpr int NC = NPAIR / CH;              // full chunks
  constexpr int REM = NPAIR - NC * CH;        // remainder pairs
  float2 bufA[CH], bufB[CH];
  f2v acc; acc.x = 0.0f; acc.y = 0.0f;
#pragma unroll
  for (int i = 0; i < CH; ++i) bufA[i] = UTPh[(size_t)(PBASE + i) * 512];
#pragma unroll 1
  for (int c = 0; c < NC; ++c) {
    const int pb = PBASE + c * CH;
    if (c + 1 < NC) {
#pragma unroll
      for (int i = 0; i < CH; ++i)
        bufB[i] = UTPh[(size_t)(pb + CH + i) * 512];
    } else if (REM > 0) {
#pragma unroll
      for (int i = 0; i < REM; ++i)
        bufB[i] = UTPh[(size_t)(pb + CH + i) * 512];
    }
#pragma unroll
    for (int i = 0; i < CH; ++i) {
      const float4 r4 = rof4[pb + i];         // ds_read_b128: pairs (2k, 2k+1)
      f2v ux; ux.x = bufA[i].x; ux.y = bufA[i].x;
      f2v uy; uy.x = bufA[i].y; uy.y = bufA[i].y;
      f2v r0; r0.x = r4.x; r0.y = r4.y;
      f2v r1; r1.x = r4.z; r1.y = r4.w;
      acc = acc + ux * r0;    // k = 2p
      acc = acc + uy * r1;    // k = 2p+1
    }
#pragma unroll
    for (int i = 0; i < CH; ++i) bufA[i] = bufB[i];
  }
#pragma unroll
  for (int i = 0; i < REM; ++i) {
    const int p = PBASE + NC * CH + i;
    const float4 r4 = rof4[p];
    f2v ux; ux.x = bufA[i].x; ux.y = bufA[i].x;
    f2v uy; uy.x = bufA[i].y; uy.y = bufA[i].y;
    f2v r0; r0.x = r4.x; r0.y = r4.y;
    f2v r1; r1.x = r4.z; r1.y = r4.w;
    acc = acc + ux * r0;
    acc = acc + uy * r1;
  }
  return acc;
}

// ---------------- Phase B: h-split pair recurrence -------------------------
// 256 blocks: bg = bid&127, half = bid>>7, partner = bid^128.
// 512 threads: pan = tid>>8 (k-panel at Eigen kc=288), hl = tid&255,
// h = half*256 + hl (500 real rows; 512-padded, pads harmless).
// Per-t r-half exchange: relaxed agent atomics, no fences.
__global__ __launch_bounds__(512) void hidden_pair(
    const float2* __restrict__ UTP, const float* __restrict__ b_h,
    const float* __restrict__ b_init, const uint32_t* __restrict__ keys,
    const float* __restrict__ wv2, uint32_t* __restrict__ hbw,
    unsigned long long* __restrict__ exch, uint32_t* __restrict__ prog) {
#pragma clang fp contract(off)
  const int tid = threadIdx.x;
  const int pan = tid >> 8;           // wave-uniform (waves 0-3 / 4-7)
  const int hl = tid & 255;
  const int bid = (int)blockIdx.x;
  const int bg = bid & 127;
  const int half = bid >> 7;
  const int partner = bid ^ 128;      // same XCD residue (mod 8)
  const int h0 = half * 256;
  const int ph0 = h0 ^ 256;
  const int h = h0 + hl;
  const int hs = (h < NH) ? h : 0;    // bias-safe row for pad lanes
  const int b0 = 2 * bg;

  __shared__ f2v rlds[512];           // FULL r (both halves), k-indexed
  __shared__ f2v ps_l[256];           // panel-1 partials
  __shared__ f2v u_l[256];            // uniforms
  __shared__ uint32_t keyl[2 * TT];

  keyl[tid] = keys[4 * (tid >> 1) + (tid & 1)];
  if (pan == 0) { f2v z; z.x = 0.0f; z.y = 0.0f; rlds[hl] = z; rlds[256 + hl] = z; }
  const float bh = b_h[hs], bi = b_init[hs];
  const float2* __restrict__ UTPh = UTP + h;
  __syncthreads();

#pragma unroll 1
  for (int t = 0; t < TT; ++t) {
    const float4* __restrict__ rof4 = (const float4*)rlds;

    f2v wvp; wvp.x = 0.0f; wvp.y = 0.0f;
    f2v a;
    if (pan == 0) {
      wvp = *(const f2v*)&wv2[((size_t)bg * TT + t) * 1024 + h * 2];
      a = dot_panel<0, 144>(UTPh, rof4);      // k = 0..287
    } else {
      a = dot_panel<144, 106>(UTPh, rof4);    // k = 288..499
      ps_l[hl] = a;
      const uint32_t k0 = keyl[2 * t], k1 = keyl[2 * t + 1];
      f2v u;
      u.x = jax_uniform(draw_bits(k0, k1, (uint32_t)(h * BB + b0)));
      u.y = jax_uniform(draw_bits(k0, k1, (uint32_t)(h * BB + b0 + 1)));
      u_l[hl] = u;
    }
    __syncthreads();

    if (pan == 0) {
      const f2v ps = ps_l[hl];
      const float acc0 = a.x + ps.x;          // == (0+panel0)+panel1
      const float acc1 = a.y + ps.y;
      const float bias = (t == 0) ? bi : bh;
      const float pre0 = (wvp.x + acc0) + bias;   // reference order
      const float pre1 = (wvp.y + acc1) + bias;
      const float pp0 = xla_sigmoid(pre0);
      const float pp1 = xla_sigmoid(pre1);
      f2v pv; pv.x = pp0; pv.y = pp1;
      rlds[h0 + hl] = pv;                     // own half update
      if (t != TT - 1) {
        // outbox: atomic store -> L2 directly (no L1 dirtiness, no fence)
        __hip_atomic_store(&exch[((size_t)bid * 2 + (t & 1)) * 256 + hl],
                           __builtin_bit_cast(unsigned long long, pv),
                           __ATOMIC_RELAXED, __HIP_MEMORY_SCOPE_AGENT);
      }
      const f2v u = u_l[hl];
      const bool hm0 = u.x < pp0;
      const bool hm1 = u.y < pp1;
      const unsigned long long m0 = __ballot(hm0);
      const unsigned long long m1 = __ballot(hm1);
      const int lh = h & 63;
      if (lh == 0) {
        uint2 w; w.x = (uint32_t)m0; w.y = (uint32_t)m1;
        *(uint2*)&hbw[(size_t)(h >> 5) * (TT * BB) + (size_t)t * BB + b0] = w;
      }
      if (lh == 32) {
        uint2 w; w.x = (uint32_t)(m0 >> 32); w.y = (uint32_t)(m1 >> 32);
        *(uint2*)&hbw[(size_t)(h >> 5) * (TT * BB) + (size_t)t * BB + b0] = w;
      }
    }
    if (t == TT - 1) break;

    // barrier drains pan0's outbox stores (vmcnt) + rlds own-half writes
    __syncthreads();
    if (tid == 0)
      __hip_atomic_store(&prog[bid * 32], (uint32_t)(t + 1),
                         __ATOMIC_RELAXED, __HIP_MEMORY_SCOPE_AGENT);
    if (pan == 1) {
      // inbox: wait partner, pull its r-half (atomic loads bypass L1)
      while (__hip_atomic_load(&prog[partner * 32], __ATOMIC_RELAXED,
                               __HIP_MEMORY_SCOPE_AGENT) < (uint32_t)(t + 1))
        __builtin_amdgcn_s_sleep(4);
      unsigned long long w = __hip_atomic_load(
          &exch[((size_t)partner * 2 + (t & 1)) * 256 + hl],
          __ATOMIC_RELAXED, __HIP_MEMORY_SCOPE_AGENT);
      rlds[ph0 + hl] = __builtin_bit_cast(f2v, w);
    }
    __syncthreads();
  }
}

// ---------------- Phase E: expand packed h bits -> out_r floats ----------------
__global__ __launch_bounds__(256) void expand_r(
    const uint32_t* __restrict__ hbw, float* __restrict__ out_r) {
  const int h = blockIdx.x;           // 0..499
  const int b = threadIdx.x;
  const uint32_t sh = (uint32_t)(h & 31);
  const uint32_t* src = hbw + (size_t)(h >> 5) * (TT * BB);
  float* dst = out_r + (size_t)h * (TT * BB);
#pragma unroll 4
  for (int t = 0; t < TT; ++t) {
    uint32_t w = src[t * BB + b];
    dst[t * BB + b] = (float)((w >> sh) & 1u);
  }
}

// ---------------- Phase C: all visible steps; h read from out_r ----------------
// fmaf(w, h, s) == s + w*h bit-exactly because h in {0,1}.
#define IT_C 16   // 784/16 = 49 i-tiles
__global__ __launch_bounds__(256) void visible_big(
    const float* __restrict__ WT, const float* __restrict__ b_v,
    const uint32_t* __restrict__ keys, const float* __restrict__ hplane,
    float* __restrict__ out_v) {
#pragma clang fp contract(off)
  const int b = threadIdx.x;
  const int i0 = blockIdx.x * IT_C;
  const int t = blockIdx.y;
  const float* hcol = hplane + (size_t)t * BB + b;  // element k: hcol[k * TT*BB]

  float acc[IT_C];
#pragma unroll
  for (int r = 0; r < IT_C; ++r) acc[r] = 0.0f;

  const int pb[3] = {0, 288, 500};
#pragma unroll 1
  for (int p = 0; p < 2; ++p) {
    float ps[IT_C];
#pragma unroll
    for (int r = 0; r < IT_C; ++r) ps[r] = 0.0f;
    const int k0 = pb[p], k1 = pb[p + 1];
#pragma unroll 8
    for (int k = k0; k < k1; ++k) {
      float hh = hcol[(size_t)k * (TT * BB)];
#pragma unroll
      for (int r = 0; r < IT_C; ++r)
        ps[r] = __builtin_fmaf(WT[(size_t)(i0 + r) * NH + k], hh, ps[r]);
    }
#pragma unroll
    for (int r = 0; r < IT_C; ++r) acc[r] = acc[r] + ps[r];
  }

  const uint32_t key0 = keys[4 * t + 2], key1 = keys[4 * t + 3];
#pragma unroll
  for (int r = 0; r < IT_C; ++r) {
    const int i = i0 + r;
    float pre = acc[r] + b_v[i];
    float p = xla_sigmoid(pre);
    uint32_t j = (uint32_t)(i * BB + b);
    float u = jax_uniform(draw_bits(key0, key1, j));
    out_v[(size_t)i * (TT * BB) + (size_t)t * BB + b] = (u < p) ? 1.0f : 0.0f;
  }
}

extern "C" void kernel_launch(void* const* d_in, const int* in_sizes, int n_in,
                              void* d_out, int out_size, void* d_ws, size_t ws_size,
                              hipStream_t stream) {
  const float* v      = (const float*)d_in[0];
  const float* W      = (const float*)d_in[1];
  const float* U      = (const float*)d_in[2];
  const float* b_h    = (const float*)d_in[3];
  const float* b_v    = (const float*)d_in[4];
  const float* b_init = (const float*)d_in[5];

  float* out_v = (float*)d_out;                       // (784,256,256) = 205.5 MB
  float* out_r = out_v + (size_t)NV * TT * BB;        // (500,256,256) = 131 MB

  // Staging inside the out_v region (dead before phase C overwrites out_v):
  //   wv2:  [128][256][512][2] f32 = 134.2 MB at offset 0
  //   exch: 256 blocks x 2 slots x 256 u64 = 1 MB after wv2
  //   prog: 256 x 32 u32 (128B-spaced) = 32 KB after exch
  // UTP (1 MB) at head of out_r region (dead before phase E overwrites out_r).
  float* wv2 = out_v;
  unsigned long long* exch =
      (unsigned long long*)(out_v + (size_t)NBG * TT * 1024);
  uint32_t* prog = (uint32_t*)(exch + (size_t)256 * 2 * 256);
  float2* UTP = (float2*)out_r;

  // ws: WT (1.57 MB) + keys (4 KB) + hbw (4.19 MB)
  float* WT = (float*)d_ws;
  uint32_t* keys = (uint32_t*)(WT + (size_t)NV * NH);
  uint32_t* hbw = keys + TT * 4;   // [16][256][256] u32

  hipMemsetAsync(prog, 0, 256 * 32 * sizeof(uint32_t), stream);
  init_keys<<<1, 256, 0, stream>>>(keys);
  wt_kernel<<<NV, 256, 0, stream>>>(W, WT);
  ut_kernel<<<250, 512, 0, stream>>>(U, UTP);

  dim3 gA(NH / HT_A, TT);
  wv_gemm<<<gA, 256, 0, stream>>>(v, W, wv2);

  hidden_pair<<<256, 512, 0, stream>>>(UTP, b_h, b_init, keys, wv2, hbw,
                                       exch, prog);

  expand_r<<<NH, 256, 0, stream>>>(hbw, out_r);

  dim3 gC(NV / IT_C, TT);
  visible_big<<<gC, 256, 0, stream>>>(WT, b_v, keys, out_r, out_v);
}

// Round 12
// 4780.959 us; speedup vs baseline: 1.7425x; 1.4126x over previous
//
#include <hip/hip_runtime.h>
#include <stdint.h>

// RTRBM CD-1: bit-exact replication of the JAX-CPU reference.
// Phase A: wv_gemm — XCD-swizzled (same-t blocks share an XCD L2), HT_A=20,
//          launch_bounds(256,4) to kill register spills, padded-LDS transpose.
// Phase B: hidden_pair — h-split block pairs, relaxed-atomic r exchange (r11).
// Phase E: expand bits -> out_r floats.
// Phase C: visible_big — same spill fix + XCD swizzle.
// Sizes: V=784, H=500, T=256, B=256. RNG: threefry partitionable.
// Eigen MT blocking (AVX no-FMA jaxlib): kc=288. K=784 -> [288,288,208]; K=500 -> [288,212].
#define NV 784
#define NH 500
#define TT 256
#define BB 256
#define NBG 128   // b-pairs

typedef float f2v __attribute__((ext_vector_type(2)));

// ---------------- threefry2x32 (JAX PRNG), exact ----------------
__device__ __forceinline__ void tf2x32(uint32_t ks0, uint32_t ks1,
                                       uint32_t x0, uint32_t x1,
                                       uint32_t& y0, uint32_t& y1) {
  uint32_t ks2 = ks0 ^ ks1 ^ 0x1BD11BDAu;
  x0 += ks0; x1 += ks1;
#define TFROT(r) { x0 += x1; x1 = (x1 << (r)) | (x1 >> (32 - (r))); x1 ^= x0; }
  TFROT(13) TFROT(15) TFROT(26) TFROT(6)
  x0 += ks1; x1 += ks2 + 1u;
  TFROT(17) TFROT(29) TFROT(16) TFROT(24)
  x0 += ks2; x1 += ks0 + 2u;
  TFROT(13) TFROT(15) TFROT(26) TFROT(6)
  x0 += ks0; x1 += ks1 + 3u;
  TFROT(17) TFROT(29) TFROT(16) TFROT(24)
  x0 += ks1; x1 += ks2 + 4u;
  TFROT(13) TFROT(15) TFROT(26) TFROT(6)
  x0 += ks2; x1 += ks0 + 5u;
#undef TFROT
  y0 = x0; y1 = x1;
}

__device__ __forceinline__ float jax_uniform(uint32_t bits) {
#pragma clang fp contract(off)
  float f = __uint_as_float((bits >> 9) | 0x3F800000u);
  return f - 1.0f;
}

// PARTITIONABLE random_bits, 32-bit: bits[j] = y0 ^ y1 of threefry(key; 0, j)
__device__ __forceinline__ uint32_t draw_bits(uint32_t k0, uint32_t k1,
                                              uint32_t j) {
  uint32_t y0, y1;
  tf2x32(k0, k1, 0u, j, y0, y1);
  return y0 ^ y1;
}

// ---------------- XLA CPU exp (Cephes/Eigen poly, no FMA) ----------------
__device__ __forceinline__ float xla_expf(float x) {
#pragma clang fp contract(off)
  float xc = fminf(fmaxf(x, -88.3762626647949f), 88.3762626647950f);
  float fx = floorf(xc * 1.44269504088896341f + 0.5f);
  float tmp = 0.693359375f * fx;
  float z = -2.12194440e-4f * fx;
  float xr = xc - tmp;
  xr = xr - z;
  z = xr * xr;
  float y = xr * 1.9875691500e-4f + 1.3981999507e-3f;
  y = y * xr + 8.3334519073e-3f;
  y = y * xr + 4.1665795894e-2f;
  y = y * xr + 1.6666665459e-1f;
  y = y * xr + 5.0000001201e-1f;
  y = y * z + xr;
  y = 1.0f + y;
  int e = (int)fx;
  float pow2 = __int_as_float((uint32_t)(e + 127) << 23);
  return y * pow2;
}

__device__ __forceinline__ float xla_sigmoid(float x) {
#pragma clang fp contract(off)
  float e = xla_expf(-x);
  float d = 1.0f + e;
  return 1.0f / d;
}

// ---------------- key derivation (PARTITIONABLE split) ----------------
__global__ void init_keys(uint32_t* __restrict__ keys /* [256][4] */) {
  int t = threadIdx.x;
  if (t >= TT) return;
  uint32_t kt0, kt1;
  tf2x32(0u, 123u, 0u, (uint32_t)t, kt0, kt1);
  uint32_t a0, a1, b0, b1;
  tf2x32(kt0, kt1, 0u, 0u, a0, a1);  // k1 (hidden)
  tf2x32(kt0, kt1, 0u, 1u, b0, b1);  // k2 (visible)
  keys[4 * t + 0] = a0;
  keys[4 * t + 1] = a1;
  keys[4 * t + 2] = b0;
  keys[4 * t + 3] = b1;
}

// ---------------- W transpose: WT[i][k] = W[k][i] ----------------
__global__ __launch_bounds__(256) void wt_kernel(const float* __restrict__ W,
                                                 float* __restrict__ WT) {
  const int i = blockIdx.x;           // 0..783
  for (int k = threadIdx.x; k < NH; k += 256)
    WT[(size_t)i * NH + k] = W[(size_t)k * NV + i];
}

// ---------------- U transpose+pair: UTP[p][h] = (U[h][2p], U[h][2p+1]) ----------------
__global__ __launch_bounds__(512) void ut_kernel(const float* __restrict__ U,
                                                 float2* __restrict__ UTP) {
  const int p = blockIdx.x;           // 0..249
  const int h = threadIdx.x;          // 0..511
  float2 w;
  if (h < NH) {
    w.x = U[(size_t)h * NH + 2 * p];
    w.y = U[(size_t)h * NH + 2 * p + 1];
  } else {
    w.x = 0.0f; w.y = 0.0f;
  }
  UTP[(size_t)p * 512 + h] = w;
}

// ---------------- Phase A: WV2[bg][t][h][2] = (W @ v_t)[h][b] ----------------
// fmaf(w, x, s) == s + w*x bit-exactly because x in {0,1} (w*x exact).
// HT_A=20 -> acc+ps = 40 live VGPRs; launch_bounds(256,4) caps VGPR at 128
// (no spill). XCD swizzle: all 25 h-tiles of one t on one XCD -> v t-slab
// (802 KB) HBM-fetched once, L2-served 20x.
#define HT_A 20   // 500/20 = 25 h-tiles per t; grid 25*256 = 6400
__global__ __launch_bounds__(256, 4) void wv_gemm(
    const float* __restrict__ v, const float* __restrict__ W,
    float* __restrict__ wv2) {
#pragma clang fp contract(off)
  const int b = threadIdx.x;
  const int bid = (int)blockIdx.x;      // 0..6399
  const int xcd = bid & 7;
  const int slot = bid >> 3;            // 0..799
  const int t = (slot / 25) * 8 + xcd;  // same-t blocks land on one XCD
  const int h0 = (slot % 25) * HT_A;
  const float* vcol = v + (size_t)t * BB + b;   // element k: vcol[k * TT*BB]

  float acc[HT_A];
#pragma unroll
  for (int r = 0; r < HT_A; ++r) acc[r] = 0.0f;

  const int pb[4] = {0, 288, 576, 784};   // kc=288 panels
#pragma unroll 1
  for (int p = 0; p < 3; ++p) {
    float ps[HT_A];
#pragma unroll
    for (int r = 0; r < HT_A; ++r) ps[r] = 0.0f;
    const int k0 = pb[p], k1 = pb[p + 1];
#pragma unroll 8
    for (int k = k0; k < k1; ++k) {
      float x = vcol[(size_t)k * (TT * BB)];
#pragma unroll
      for (int r = 0; r < HT_A; ++r)
        ps[r] = __builtin_fmaf(W[(size_t)(h0 + r) * NV + k], x, ps[r]);
    }
#pragma unroll
    for (int r = 0; r < HT_A; ++r) acc[r] = acc[r] + ps[r];
  }

  // LDS transpose (PADDED: 257 -> bank = (row + col) % 32, conflict-light)
  __shared__ float al[HT_A][BB + 1];
#pragma unroll
  for (int r = 0; r < HT_A; ++r) al[r][b] = acc[r];
  __syncthreads();

  // write 40-float runs: wv2[bg][t][h0*2 .. h0*2+39]
  const int sub = b / 40;         // 0..5 (6 bg per iter), b<240 active
  const int idx = b % 40;         // h = h0 + idx/2, j = idx&1
#pragma unroll 1
  for (int it = 0; it < 22; ++it) {
    const int bg = it * 6 + sub;
    if (b < 240 && bg < NBG) {
      wv2[((size_t)bg * TT + t) * 1024 + h0 * 2 + idx] =
          al[idx >> 1][2 * bg + (idx & 1)];
    }
  }
}

// ---------------- Phase B dot: software-pipelined panel dot ----------------
// Strict ascending k (k = 2p then 2p+1), mul-then-add (no FMA: r arbitrary).
// UTP loads double-buffered in registers, statically indexed throughout.
template <int PBASE, int NPAIR>
__device__ __forceinline__ f2v dot_panel(const float2* __restrict__ UTPh,
                                         const float4* __restrict__ rof4) {
#pragma clang fp contract(off)
  constexpr int CH = 8;
  constexpr int NC = NPAIR / CH;              // full chunks
  constexpr int REM = NPAIR - NC * CH;        // remainder pairs
  float2 bufA[CH], bufB[CH];
  f2v acc; acc.x = 0.0f; acc.y = 0.0f;
#pragma unroll
  for (int i = 0; i < CH; ++i) bufA[i] = UTPh[(size_t)(PBASE + i) * 512];
#pragma unroll 1
  for (int c = 0; c < NC; ++c) {
    const int pb = PBASE + c * CH;
    if (c + 1 < NC) {
#pragma unroll
      for (int i = 0; i < CH; ++i)
        bufB[i] = UTPh[(size_t)(pb + CH + i) * 512];
    } else if (REM > 0) {
#pragma unroll
      for (int i = 0; i < REM; ++i)
        bufB[i] = UTPh[(size_t)(pb + CH + i) * 512];
    }
#pragma unroll
    for (int i = 0; i < CH; ++i) {
      const float4 r4 = rof4[pb + i];         // ds_read_b128: pairs (2k, 2k+1)
      f2v ux; ux.x = bufA[i].x; ux.y = bufA[i].x;
      f2v uy; uy.x = bufA[i].y; uy.y = bufA[i].y;
      f2v r0; r0.x = r4.x; r0.y = r4.y;
      f2v r1; r1.x = r4.z; r1.y = r4.w;
      acc = acc + ux * r0;    // k = 2p
      acc = acc + uy * r1;    // k = 2p+1
    }
#pragma unroll
    for (int i = 0; i < CH; ++i) bufA[i] = bufB[i];
  }
#pragma unroll
  for (int i = 0; i < REM; ++i) {
    const int p = PBASE + NC * CH + i;
    const float4 r4 = rof4[p];
    f2v ux; ux.x = bufA[i].x; ux.y = bufA[i].x;
    f2v uy; uy.x = bufA[i].y; uy.y = bufA[i].y;
    f2v r0; r0.x = r4.x; r0.y = r4.y;
    f2v r1; r1.x = r4.z; r1.y = r4.w;
    acc = acc + ux * r0;
    acc = acc + uy * r1;
  }
  return acc;
}

// ---------------- Phase B: h-split pair recurrence -------------------------
// 256 blocks: bg = bid&127, half = bid>>7, partner = bid^128.
// 512 threads: pan = tid>>8 (k-panel at Eigen kc=288), hl = tid&255,
// h = half*256 + hl (500 real rows; 512-padded, pads harmless).
// Per-t r-half exchange: relaxed agent atomics, no fences.
__global__ __launch_bounds__(512) void hidden_pair(
    const float2* __restrict__ UTP, const float* __restrict__ b_h,
    const float* __restrict__ b_init, const uint32_t* __restrict__ keys,
    const float* __restrict__ wv2, uint32_t* __restrict__ hbw,
    unsigned long long* __restrict__ exch, uint32_t* __restrict__ prog) {
#pragma clang fp contract(off)
  const int tid = threadIdx.x;
  const int pan = tid >> 8;           // wave-uniform (waves 0-3 / 4-7)
  const int hl = tid & 255;
  const int bid = (int)blockIdx.x;
  const int bg = bid & 127;
  const int half = bid >> 7;
  const int partner = bid ^ 128;      // same XCD residue (mod 8)
  const int h0 = half * 256;
  const int ph0 = h0 ^ 256;
  const int h = h0 + hl;
  const int hs = (h < NH) ? h : 0;    // bias-safe row for pad lanes
  const int b0 = 2 * bg;

  __shared__ f2v rlds[512];           // FULL r (both halves), k-indexed
  __shared__ f2v ps_l[256];           // panel-1 partials
  __shared__ f2v u_l[256];            // uniforms
  __shared__ uint32_t keyl[2 * TT];

  keyl[tid] = keys[4 * (tid >> 1) + (tid & 1)];
  if (pan == 0) { f2v z; z.x = 0.0f; z.y = 0.0f; rlds[hl] = z; rlds[256 + hl] = z; }
  const float bh = b_h[hs], bi = b_init[hs];
  const float2* __restrict__ UTPh = UTP + h;
  __syncthreads();

#pragma unroll 1
  for (int t = 0; t < TT; ++t) {
    const float4* __restrict__ rof4 = (const float4*)rlds;

    f2v wvp; wvp.x = 0.0f; wvp.y = 0.0f;
    f2v a;
    if (pan == 0) {
      wvp = *(const f2v*)&wv2[((size_t)bg * TT + t) * 1024 + h * 2];
      a = dot_panel<0, 144>(UTPh, rof4);      // k = 0..287
    } else {
      a = dot_panel<144, 106>(UTPh, rof4);    // k = 288..499
      ps_l[hl] = a;
      const uint32_t k0 = keyl[2 * t], k1 = keyl[2 * t + 1];
      f2v u;
      u.x = jax_uniform(draw_bits(k0, k1, (uint32_t)(h * BB + b0)));
      u.y = jax_uniform(draw_bits(k0, k1, (uint32_t)(h * BB + b0 + 1)));
      u_l[hl] = u;
    }
    __syncthreads();

    if (pan == 0) {
      const f2v ps = ps_l[hl];
      const float acc0 = a.x + ps.x;          // == (0+panel0)+panel1
      const float acc1 = a.y + ps.y;
      const float bias = (t == 0) ? bi : bh;
      const float pre0 = (wvp.x + acc0) + bias;   // reference order
      const float pre1 = (wvp.y + acc1) + bias;
      const float pp0 = xla_sigmoid(pre0);
      const float pp1 = xla_sigmoid(pre1);
      f2v pv; pv.x = pp0; pv.y = pp1;
      rlds[h0 + hl] = pv;                     // own half update
      if (t != TT - 1) {
        // outbox: atomic store -> L2 directly (no L1 dirtiness, no fence)
        __hip_atomic_store(&exch[((size_t)bid * 2 + (t & 1)) * 256 + hl],
                           __builtin_bit_cast(unsigned long long, pv),
                           __ATOMIC_RELAXED, __HIP_MEMORY_SCOPE_AGENT);
      }
      const f2v u = u_l[hl];
      const bool hm0 = u.x < pp0;
      const bool hm1 = u.y < pp1;
      const unsigned long long m0 = __ballot(hm0);
      const unsigned long long m1 = __ballot(hm1);
      const int lh = h & 63;
      if (lh == 0) {
        uint2 w; w.x = (uint32_t)m0; w.y = (uint32_t)m1;
        *(uint2*)&hbw[(size_t)(h >> 5) * (TT * BB) + (size_t)t * BB + b0] = w;
      }
      if (lh == 32) {
        uint2 w; w.x = (uint32_t)(m0 >> 32); w.y = (uint32_t)(m1 >> 32);
        *(uint2*)&hbw[(size_t)(h >> 5) * (TT * BB) + (size_t)t * BB + b0] = w;
      }
    }
    if (t == TT - 1) break;

    // barrier drains pan0's outbox stores (vmcnt) + rlds own-half writes
    __syncthreads();
    if (tid == 0)
      __hip_atomic_store(&prog[bid * 32], (uint32_t)(t + 1),
                         __ATOMIC_RELAXED, __HIP_MEMORY_SCOPE_AGENT);
    if (pan == 1) {
      // inbox: wait partner, pull its r-half (atomic loads bypass L1)
      while (__hip_atomic_load(&prog[partner * 32], __ATOMIC_RELAXED,
                               __HIP_MEMORY_SCOPE_AGENT) < (uint32_t)(t + 1))
        __builtin_amdgcn_s_sleep(4);
      unsigned long long w = __hip_atomic_load(
          &exch[((size_t)partner * 2 + (t & 1)) * 256 + hl],
          __ATOMIC_RELAXED, __HIP_MEMORY_SCOPE_AGENT);
      rlds[ph0 + hl] = __builtin_bit_cast(f2v, w);
    }
    __syncthreads();
  }
}

// ---------------- Phase E: expand packed h bits -> out_r floats ----------------
__global__ __launch_bounds__(256) void expand_r(
    const uint32_t* __restrict__ hbw, float* __restrict__ out_r) {
  const int h = blockIdx.x;           // 0..499
  const int b = threadIdx.x;
  const uint32_t sh = (uint32_t)(h & 31);
  const uint32_t* src = hbw + (size_t)(h >> 5) * (TT * BB);
  float* dst = out_r + (size_t)h * (TT * BB);
#pragma unroll 4
  for (int t = 0; t < TT; ++t) {
    uint32_t w = src[t * BB + b];
    dst[t * BB + b] = (float)((w >> sh) & 1u);
  }
}

// ---------------- Phase C: all visible steps; h read from out_r ----------------
// fmaf(w, h, s) == s + w*h bit-exactly because h in {0,1}.
// Same spill fix (launch_bounds) + XCD swizzle (same-t blocks on one XCD).
#define IT_C 16   // 784/16 = 49 i-tiles; grid 49*256 = 12544
__global__ __launch_bounds__(256, 4) void visible_big(
    const float* __restrict__ WT, const float* __restrict__ b_v,
    const uint32_t* __restrict__ keys, const float* __restrict__ hplane,
    float* __restrict__ out_v) {
#pragma clang fp contract(off)
  const int b = threadIdx.x;
  const int bid = (int)blockIdx.x;      // 0..12543
  const int xcd = bid & 7;
  const int slot = bid >> 3;            // 0..1567
  const int t = (slot / 49) * 8 + xcd;  // same-t blocks land on one XCD
  const int i0 = (slot % 49) * IT_C;
  const float* hcol = hplane + (size_t)t * BB + b;  // element k: hcol[k * TT*BB]

  float acc[IT_C];
#pragma unroll
  for (int r = 0; r < IT_C; ++r) acc[r] = 0.0f;

  const int pb[3] = {0, 288, 500};
#pragma unroll 1
  for (int p = 0; p < 2; ++p) {
    float ps[IT_C];
#pragma unroll
    for (int r = 0; r < IT_C; ++r) ps[r] = 0.0f;
    const int k0 = pb[p], k1 = pb[p + 1];
#pragma unroll 8
    for (int k = k0; k < k1; ++k) {
      float hh = hcol[(size_t)k * (TT * BB)];
#pragma unroll
      for (int r = 0; r < IT_C; ++r)
        ps[r] = __builtin_fmaf(WT[(size_t)(i0 + r) * NH + k], hh, ps[r]);
    }
#pragma unroll
    for (int r = 0; r < IT_C; ++r) acc[r] = acc[r] + ps[r];
  }

  const uint32_t key0 = keys[4 * t + 2], key1 = keys[4 * t + 3];
#pragma unroll
  for (int r = 0; r < IT_C; ++r) {
    const int i = i0 + r;
    float pre = acc[r] + b_v[i];
    float p = xla_sigmoid(pre);
    uint32_t j = (uint32_t)(i * BB + b);
    float u = jax_uniform(draw_bits(key0, key1, j));
    out_v[(size_t)i * (TT * BB) + (size_t)t * BB + b] = (u < p) ? 1.0f : 0.0f;
  }
}

extern "C" void kernel_launch(void* const* d_in, const int* in_sizes, int n_in,
                              void* d_out, int out_size, void* d_ws, size_t ws_size,
                              hipStream_t stream) {
  const float* v      = (const float*)d_in[0];
  const float* W      = (const float*)d_in[1];
  const float* U      = (const float*)d_in[2];
  const float* b_h    = (const float*)d_in[3];
  const float* b_v    = (const float*)d_in[4];
  const float* b_init = (const float*)d_in[5];

  float* out_v = (float*)d_out;                       // (784,256,256) = 205.5 MB
  float* out_r = out_v + (size_t)NV * TT * BB;        // (500,256,256) = 131 MB

  // Staging inside the out_v region (dead before phase C overwrites out_v):
  //   wv2:  [128][256][512][2] f32 = 134.2 MB at offset 0
  //   exch: 256 blocks x 2 slots x 256 u64 = 1 MB after wv2
  //   prog: 256 x 32 u32 (128B-spaced) = 32 KB after exch
  // UTP (1 MB) at head of out_r region (dead before phase E overwrites out_r).
  float* wv2 = out_v;
  unsigned long long* exch =
      (unsigned long long*)(out_v + (size_t)NBG * TT * 1024);
  uint32_t* prog = (uint32_t*)(exch + (size_t)256 * 2 * 256);
  float2* UTP = (float2*)out_r;

  // ws: WT (1.57 MB) + keys (4 KB) + hbw (4.19 MB)
  float* WT = (float*)d_ws;
  uint32_t* keys = (uint32_t*)(WT + (size_t)NV * NH);
  uint32_t* hbw = keys + TT * 4;   // [16][256][256] u32

  hipMemsetAsync(prog, 0, 256 * 32 * sizeof(uint32_t), stream);
  init_keys<<<1, 256, 0, stream>>>(keys);
  wt_kernel<<<NV, 256, 0, stream>>>(W, WT);
  ut_kernel<<<250, 512, 0, stream>>>(U, UTP);

  wv_gemm<<<25 * TT, 256, 0, stream>>>(v, W, wv2);

  hidden_pair<<<256, 512, 0, stream>>>(UTP, b_h, b_init, keys, wv2, hbw,
                                       exch, prog);

  expand_r<<<NH, 256, 0, stream>>>(hbw, out_r);

  visible_big<<<49 * TT, 256, 0, stream>>>(WT, b_v, keys, out_r, out_v);
}